// Round 1
// baseline (498.984 us; speedup 1.0000x reference)
//
#include <hip/hip_runtime.h>
#include <math.h>

// Problem constants: B=4, H=16, L=1024, scales ws={2,4,8}, HIDDEN=32
#define L_DIM 1024
#define BH 64                      // B*H
#define ROWS (BH * L_DIM)          // 65536 rows per attn tensor

// native vector type — __builtin_nontemporal_load requires scalar/native-vector
// pointee (HIP's float4 wrapper is rejected)
typedef float floatx4 __attribute__((ext_vector_type(4)));

// ---------------------------------------------------------------------------
// Fully fused kernel. One block = 8 consecutive rows (one ws=8 window) of one
// (b,h) — ws={2,4,8} window boundaries all align at multiples of 8 rows, so a
// block is self-contained: row stats -> window MLPs -> blended output, with
// stats in 256 B of LDS instead of a 2 MiB global workspace.
//
// Phase 1: 8 waves, one row-pair (attn_1 row r + attn_2 row r) per wave.
//          Each lane: 4+4 nontemporal float4 loads (coalesced 1 KiB/instr),
//          butterfly shuffle-reduce 8 quantities, lane 0 writes stats to LDS.
// Phase 2: wave 0 lanes 0-3 run the 4 ws=2 MLPs, wave 1 lanes 0-1 the 2 ws=4
//          MLPs, wave 2 lane 0 the ws=8 MLP. Scale index is a compile-time
//          template param -> weight reads are scalar s_load through K$.
// Phase 3: threads 0-7 blend the 3 alphas with softmax(scale_weights) and
//          store 8 contiguous floats.
// ---------------------------------------------------------------------------

template <int S, int WS>
__device__ __forceinline__ void run_mlp(
    const float (*sm)[8], int base,
    const float* __restrict__ W1, const float* __restrict__ b1,
    const float* __restrict__ W2, const float* __restrict__ b2,
    const float* __restrict__ W3, const float* __restrict__ b3,
    float* dst)
{
    // weight bases: compile-time scale offset on an SGPR kernarg -> s_load path
    const float* __restrict__ W1p = W1 + S * 256;   // [32][8]
    const float* __restrict__ b1p = b1 + S * 32;
    const float* __restrict__ W2p = W2 + S * 512;   // [16][32]
    const float* __restrict__ b2p = b2 + S * 16;
    const float* __restrict__ W3p = W3 + S * 16;    // [1][16]
    const float  b3v = b3[S];

    float g[8] = {0.f, 0.f, 0.f, 0.f, 0.f, 0.f, 0.f, 0.f};
#pragma unroll
    for (int j = 0; j < WS; ++j)
#pragma unroll
        for (int k = 0; k < 8; ++k) g[k] += sm[base + j][k];
    const float inv = 1.0f / (float)WS;
#pragma unroll
    for (int k = 0; k < 8; ++k) g[k] *= inv;

    // MLP 8 -> 32 -> 16 -> 1 (relu, relu, sigmoid)
    float h1[32];
#pragma unroll
    for (int o = 0; o < 32; ++o) {
        float acc = b1p[o];
#pragma unroll
        for (int f = 0; f < 8; ++f) acc += W1p[o * 8 + f] * g[f];
        h1[o] = fmaxf(acc, 0.f);
    }
    float h2[16];
#pragma unroll
    for (int o = 0; o < 16; ++o) {
        float acc = b2p[o];
#pragma unroll
        for (int f = 0; f < 32; ++f) acc += W2p[o * 32 + f] * h1[f];
        h2[o] = fmaxf(acc, 0.f);
    }
    float acc = b3v;
#pragma unroll
    for (int f = 0; f < 16; ++f) acc += W3p[f] * h2[f];

    *dst = 1.0f / (1.0f + expf(-acc));
}

__global__ __launch_bounds__(512) void fused_gate_kernel(
    const float* __restrict__ a1, const float* __restrict__ a2,
    const float* __restrict__ W1, const float* __restrict__ b1,
    const float* __restrict__ W2, const float* __restrict__ b2,
    const float* __restrict__ W3, const float* __restrict__ b3,
    const float* __restrict__ sw,
    float* __restrict__ out)
{
    __shared__ float sm[8][8];  // per local row: mean1,std1,max1,min1,mean2,std2,max2,min2
    __shared__ float aw[8];     // alphas: [0..3]=ws2 windows, [4..5]=ws4, [6]=ws8

    const int wave = threadIdx.x >> 6;
    const int lane = threadIdx.x & 63;
    const int r = (blockIdx.x << 3) | wave;   // global row (bh*1024 + l), 8|1024 so bh uniform

    const floatx4* __restrict__ r1 = (const floatx4*)(a1 + (size_t)r * L_DIM);
    const floatx4* __restrict__ r2 = (const floatx4*)(a2 + (size_t)r * L_DIM);

    // ---- Phase 1: per-row stats for both tensors --------------------------
    float s1 = 0.f, q1 = 0.f, mx1 = -INFINITY, mn1 = INFINITY;
    float s2 = 0.f, q2 = 0.f, mx2 = -INFINITY, mn2 = INFINITY;
#pragma unroll
    for (int c = 0; c < 4; ++c) {
        floatx4 v = __builtin_nontemporal_load(&r1[(c << 6) + lane]);
        floatx4 u = __builtin_nontemporal_load(&r2[(c << 6) + lane]);
        s1 += v.x + v.y + v.z + v.w;
        q1 += v.x * v.x + v.y * v.y + v.z * v.z + v.w * v.w;
        mx1 = fmaxf(mx1, fmaxf(fmaxf(v.x, v.y), fmaxf(v.z, v.w)));
        mn1 = fminf(mn1, fminf(fminf(v.x, v.y), fminf(v.z, v.w)));
        s2 += u.x + u.y + u.z + u.w;
        q2 += u.x * u.x + u.y * u.y + u.z * u.z + u.w * u.w;
        mx2 = fmaxf(mx2, fmaxf(fmaxf(u.x, u.y), fmaxf(u.z, u.w)));
        mn2 = fminf(mn2, fminf(fminf(u.x, u.y), fminf(u.z, u.w)));
    }
#pragma unroll
    for (int off = 32; off > 0; off >>= 1) {
        s1 += __shfl_xor(s1, off, 64);
        q1 += __shfl_xor(q1, off, 64);
        mx1 = fmaxf(mx1, __shfl_xor(mx1, off, 64));
        mn1 = fminf(mn1, __shfl_xor(mn1, off, 64));
        s2 += __shfl_xor(s2, off, 64);
        q2 += __shfl_xor(q2, off, 64);
        mx2 = fmaxf(mx2, __shfl_xor(mx2, off, 64));
        mn2 = fminf(mn2, __shfl_xor(mn2, off, 64));
    }
    if (lane == 0) {
        const float invL = 1.0f / (float)L_DIM;
        const float invN = 1.0f / (float)(L_DIM - 1);   // ddof=1
        float m1 = s1 * invL, m2 = s2 * invL;
        float v1 = fmaxf((q1 - s1 * s1 * invL) * invN, 0.f);
        float v2 = fmaxf((q2 - s2 * s2 * invL) * invN, 0.f);
        sm[wave][0] = m1; sm[wave][1] = sqrtf(v1); sm[wave][2] = mx1; sm[wave][3] = mn1;
        sm[wave][4] = m2; sm[wave][5] = sqrtf(v2); sm[wave][6] = mx2; sm[wave][7] = mn2;
    }
    __syncthreads();

    // ---- Phase 2: window MLPs, one scale per wave (scale is compile-time) -
    if (wave == 0) {
        if (lane < 4) run_mlp<0, 2>(sm, lane << 1, W1, b1, W2, b2, W3, b3, &aw[lane]);
    } else if (wave == 1) {
        if (lane < 2) run_mlp<1, 4>(sm, lane << 2, W1, b1, W2, b2, W3, b3, &aw[4 + lane]);
    } else if (wave == 2) {
        if (lane == 0) run_mlp<2, 8>(sm, 0, W1, b1, W2, b2, W3, b3, &aw[6]);
    }
    __syncthreads();

    // ---- Phase 3: softmax-weighted blend, 8 outputs per block -------------
    if (threadIdx.x < 8) {
        const float t0 = sw[0], t1 = sw[1], t2 = sw[2];
        const float m = fmaxf(t0, fmaxf(t1, t2));
        const float e0 = expf(t0 - m), e1 = expf(t1 - m), e2 = expf(t2 - m);
        const float einv = 1.0f / (e0 + e1 + e2);
        out[(blockIdx.x << 3) + threadIdx.x] =
              (e0 * einv) * aw[threadIdx.x >> 1]
            + (e1 * einv) * aw[4 + (threadIdx.x >> 2)]
            + (e2 * einv) * aw[6];
    }
}

extern "C" void kernel_launch(void* const* d_in, const int* in_sizes, int n_in,
                              void* d_out, int out_size, void* d_ws, size_t ws_size,
                              hipStream_t stream) {
    const float* attn1 = (const float*)d_in[0];
    const float* attn2 = (const float*)d_in[1];
    const float* W1 = (const float*)d_in[2];
    const float* b1 = (const float*)d_in[3];
    const float* W2 = (const float*)d_in[4];
    const float* b2 = (const float*)d_in[5];
    const float* W3 = (const float*)d_in[6];
    const float* b3 = (const float*)d_in[7];
    const float* sw = (const float*)d_in[8];
    float* out = (float*)d_out;

    // single fused dispatch: 8192 blocks x 512 threads, 8 rows (both tensors)
    // per block; no workspace usage at all
    fused_gate_kernel<<<ROWS / 8, 512, 0, stream>>>(
        attn1, attn2, W1, b1, W2, b2, W3, b3, sw, out);
}